// Round 8
// baseline (93.861 us; speedup 1.0000x reference)
//
#include <hip/hip_runtime.h>

#define NB 64
#define NA 256
#define NT 2048
#define NK 16
#define CAP 32                 // P(row candidates > 32) ~ 2e-11 (Binomial(2048,1/256))
#define NROWS (NB * NA)
#define WAVES 8
#define APG (NA / WAVES)       // 32 atoms per wave-group

typedef float f32x4 __attribute__((ext_vector_type(4)));

// k1: 512 threads = 8 waves over one 256-wide t-tile; wave ag owns atoms
// [ag*32, ag*32+32). Regular (cached) float4 loads — nt-loads measured -24%
// on gfx950 (R6) — and non-temporal stores for the streaming mask write.
// feat-zeroing moved to hipMemsetAsync (pure fill runs ~7 TB/s vs mixed).
// LDS reduction across the 8 groups, then the group-0 wave scatters each
// column's winner into the per-(b,a) candidate list.
__global__ __launch_bounds__(512) void k1_argmax(
    const float* __restrict__ x, const float* __restrict__ thr_p,
    float* __restrict__ mask,
    int* __restrict__ counts, unsigned long long* __restrict__ lists) {
    const float thr = thr_p[0];
    const int lane = threadIdx.x & 63;
    const int ag   = threadIdx.x >> 6;
    const int t0   = blockIdx.x * 256 + lane * 4;   // 4 t's per lane
    const int b    = blockIdx.y;
    const size_t bo = (size_t)b * NA * NT;
    const f32x4* xb = (const f32x4*)(x + bo);
    f32x4* mb = (f32x4*)(mask + bo);
    const int v4 = t0 >> 2;                          // float4 index within a row

    float mv0 = 0.f, mv1 = 0.f, mv2 = 0.f, mv3 = 0.f;  // thresholded max (>=0)
    int   mi0 = 0,   mi1 = 0,   mi2 = 0,   mi3 = 0;
    const int a0 = ag * APG;
    #pragma unroll 8
    for (int j = 0; j < APG; ++j) {
        const int a = a0 + j;
        const int off = a * (NT / 4) + v4;
        const f32x4 v = xb[off];
        f32x4 m;
        m.x = (v.x >= thr) ? 1.f : 0.f;
        m.y = (v.y >= thr) ? 1.f : 0.f;
        m.z = (v.z >= thr) ? 1.f : 0.f;
        m.w = (v.w >= thr) ? 1.f : 0.f;
        __builtin_nontemporal_store(m, &mb[off]);
        const float vt0 = (v.x >= thr) ? v.x : 0.f;
        const float vt1 = (v.y >= thr) ? v.y : 0.f;
        const float vt2 = (v.z >= thr) ? v.z : 0.f;
        const float vt3 = (v.w >= thr) ? v.w : 0.f;
        if (vt0 > mv0) { mv0 = vt0; mi0 = a; }   // strict >: lowest atom wins ties
        if (vt1 > mv1) { mv1 = vt1; mi1 = a; }
        if (vt2 > mv2) { mv2 = vt2; mi2 = a; }
        if (vt3 > mv3) { mv3 = vt3; mi3 = a; }
    }

    __shared__ f32x4 sv[WAVES][64];
    __shared__ int4  si[WAVES][64];
    sv[ag][lane] = (f32x4){mv0, mv1, mv2, mv3};
    si[ag][lane] = make_int4(mi0, mi1, mi2, mi3);
    __syncthreads();
    if (ag == 0) {
        float bv0 = mv0, bv1 = mv1, bv2 = mv2, bv3 = mv3;
        int   bi0 = mi0, bi1 = mi1, bi2 = mi2, bi3 = mi3;
        #pragma unroll
        for (int g = 1; g < WAVES; ++g) {        // ascending: strict > keeps lower group
            const f32x4 gv = sv[g][lane];
            const int4  gi = si[g][lane];
            if (gv.x > bv0) { bv0 = gv.x; bi0 = gi.x; }
            if (gv.y > bv1) { bv1 = gv.y; bi1 = gi.y; }
            if (gv.z > bv2) { bv2 = gv.z; bi2 = gi.z; }
            if (gv.w > bv3) { bv3 = gv.w; bi3 = gi.w; }
        }
        #pragma unroll
        for (int e = 0; e < 4; ++e) {
            const float bv = (e == 0) ? bv0 : (e == 1) ? bv1 : (e == 2) ? bv2 : bv3;
            const int   bi = (e == 0) ? bi0 : (e == 1) ? bi1 : (e == 2) ? bi2 : bi3;
            if (bv > 0.f) {
                const int row = b * NA + bi;
                const int pos = atomicAdd(&counts[row], 1);
                if (pos < CAP) {
                    const unsigned long long key =
                        ((unsigned long long)__float_as_uint(bv) << 32) |
                        (unsigned)(~(t0 + e));
                    lists[(size_t)row * CAP + pos] = key;
                }
            }
        }
    }
}

// k2: one THREAD per row. Top-16 of the ~8 candidates via 16-slot register
// insertion (keys order by value desc, tie -> lower t), zero-fill via a
// per-thread LDS bitmap of candidate t's.
__global__ __launch_bounds__(64) void k2_select(
    const int* __restrict__ counts, const unsigned long long* __restrict__ lists,
    float* __restrict__ feat, float* __restrict__ idx_out) {
    __shared__ unsigned bm[64][65];              // +1 pad: (lane+w)%32 banks
    const int lane = threadIdx.x;
    const int row  = blockIdx.x * 64 + lane;
    unsigned* mybm = bm[lane];
    #pragma unroll
    for (int w = 0; w < NT / 32; ++w) mybm[w] = 0u;

    int n = counts[row];
    if (n > CAP) n = CAP;
    const unsigned long long* L = lists + (size_t)row * CAP;

    unsigned long long best[NK];
    #pragma unroll
    for (int k = 0; k < NK; ++k) best[k] = 0ull;

    for (int i = 0; i < n; ++i) {
        unsigned long long c = L[i];
        const unsigned t = ~(unsigned)c & (NT - 1);
        mybm[t >> 5] |= 1u << (t & 31);
        #pragma unroll
        for (int k = 0; k < NK; ++k) {           // bubble c down (static indices)
            const unsigned long long hi = best[k] > c ? best[k] : c;
            const unsigned long long lo = best[k] > c ? c : best[k];
            best[k] = hi; c = lo;
        }
    }

    const int nsel = (n < NK) ? n : NK;
    float* frow = feat + (size_t)row * NT;
    float* irow = idx_out + (size_t)row * NK;
    #pragma unroll
    for (int k = 0; k < NK; ++k) {
        if (k < nsel) {
            const unsigned t = ~(unsigned)best[k] & (NT - 1);
            irow[k] = (float)t;
            frow[t] = 1.0f;
        }
    }
    // zero-fill: smallest t's not in the candidate set
    int k = nsel;
    for (int w = 0; w < NT / 32 && k < NK; ++w) {
        unsigned z = ~mybm[w];
        while (z && k < NK) {
            const int bit = __ffs(z) - 1;
            z &= z - 1;
            const int t = w * 32 + bit;
            irow[k] = (float)t;
            frow[t] = 1.0f;
            ++k;
        }
    }
}

extern "C" void kernel_launch(void* const* d_in, const int* in_sizes, int n_in,
                              void* d_out, int out_size, void* d_ws, size_t ws_size,
                              hipStream_t stream) {
    const float* x   = (const float*)d_in[0];
    const float* thr = (const float*)d_in[1];

    float* feat    = (float*)d_out;                       // [B,A,T]
    float* idx_out = feat + (size_t)NB * NA * NT;         // [B,A,K] (indices as float)
    float* mask    = idx_out + (size_t)NB * NA * NK;      // [B,A,T]

    int* counts = (int*)d_ws;                                           // [NROWS]
    unsigned long long* lists =
        (unsigned long long*)((char*)d_ws + 65536);                     // [NROWS][CAP]

    (void)hipMemsetAsync(counts, 0, sizeof(int) * NROWS, stream);
    (void)hipMemsetAsync(feat, 0, sizeof(float) * (size_t)NB * NA * NT, stream);
    hipLaunchKernelGGL(k1_argmax, dim3(NT / 256, NB), dim3(512), 0, stream,
                       x, thr, mask, counts, lists);
    hipLaunchKernelGGL(k2_select, dim3(NROWS / 64), dim3(64), 0, stream,
                       counts, lists, feat, idx_out);
}

// Round 9
// 79.693 us; speedup vs baseline: 1.1778x; 1.1778x over previous
//
#include <hip/hip_runtime.h>

#define NB 64
#define NA 256
#define NT 2048
#define NK 16
#define CAP 32                 // P(row candidates > 32) ~ 2e-11 (Binomial(2048,1/256))
#define NROWS (NB * NA)
#define WAVES 8
#define APG (NA / WAVES)       // 32 atoms per wave-group

typedef float f32x4 __attribute__((ext_vector_type(4)));

// k1: 512 threads = 8 waves over one 256-wide t-tile; wave ag owns atoms
// [ag*32, ag*32+32). Regular (cached) float4 loads — nt-loads measured -24%
// on gfx950 (R6) — and non-temporal stores for the 268 MB of streaming
// writes (feat zeros + mask); memset-split of feat measured -17% (R8).
// LDS reduction across the 8 groups, then the group-0 wave scatters each
// column's winner into the per-(b,a) candidate list.
__global__ __launch_bounds__(512) void k1_argmax(
    const float* __restrict__ x, const float* __restrict__ thr_p,
    float* __restrict__ feat, float* __restrict__ mask,
    int* __restrict__ counts, unsigned long long* __restrict__ lists) {
    const float thr = thr_p[0];
    const int lane = threadIdx.x & 63;
    const int ag   = threadIdx.x >> 6;
    const int t0   = blockIdx.x * 256 + lane * 4;   // 4 t's per lane
    const int b    = blockIdx.y;
    const size_t bo = (size_t)b * NA * NT;
    const f32x4* xb = (const f32x4*)(x + bo);
    f32x4* fb = (f32x4*)(feat + bo);
    f32x4* mb = (f32x4*)(mask + bo);
    const int v4 = t0 >> 2;                          // float4 index within a row

    float mv0 = 0.f, mv1 = 0.f, mv2 = 0.f, mv3 = 0.f;  // thresholded max (>=0)
    int   mi0 = 0,   mi1 = 0,   mi2 = 0,   mi3 = 0;
    const int a0 = ag * APG;
    const f32x4 zero4 = {0.f, 0.f, 0.f, 0.f};
    #pragma unroll 8
    for (int j = 0; j < APG; ++j) {
        const int a = a0 + j;
        const int off = a * (NT / 4) + v4;
        const f32x4 v = xb[off];
        f32x4 m;
        m.x = (v.x >= thr) ? 1.f : 0.f;
        m.y = (v.y >= thr) ? 1.f : 0.f;
        m.z = (v.z >= thr) ? 1.f : 0.f;
        m.w = (v.w >= thr) ? 1.f : 0.f;
        __builtin_nontemporal_store(m, &mb[off]);
        __builtin_nontemporal_store(zero4, &fb[off]);
        const float vt0 = (v.x >= thr) ? v.x : 0.f;
        const float vt1 = (v.y >= thr) ? v.y : 0.f;
        const float vt2 = (v.z >= thr) ? v.z : 0.f;
        const float vt3 = (v.w >= thr) ? v.w : 0.f;
        if (vt0 > mv0) { mv0 = vt0; mi0 = a; }   // strict >: lowest atom wins ties
        if (vt1 > mv1) { mv1 = vt1; mi1 = a; }
        if (vt2 > mv2) { mv2 = vt2; mi2 = a; }
        if (vt3 > mv3) { mv3 = vt3; mi3 = a; }
    }

    __shared__ f32x4 sv[WAVES][64];
    __shared__ int4  si[WAVES][64];
    sv[ag][lane] = (f32x4){mv0, mv1, mv2, mv3};
    si[ag][lane] = make_int4(mi0, mi1, mi2, mi3);
    __syncthreads();
    if (ag == 0) {
        float bv0 = mv0, bv1 = mv1, bv2 = mv2, bv3 = mv3;
        int   bi0 = mi0, bi1 = mi1, bi2 = mi2, bi3 = mi3;
        #pragma unroll
        for (int g = 1; g < WAVES; ++g) {        // ascending: strict > keeps lower group
            const f32x4 gv = sv[g][lane];
            const int4  gi = si[g][lane];
            if (gv.x > bv0) { bv0 = gv.x; bi0 = gi.x; }
            if (gv.y > bv1) { bv1 = gv.y; bi1 = gi.y; }
            if (gv.z > bv2) { bv2 = gv.z; bi2 = gi.z; }
            if (gv.w > bv3) { bv3 = gv.w; bi3 = gi.w; }
        }
        #pragma unroll
        for (int e = 0; e < 4; ++e) {
            const float bv = (e == 0) ? bv0 : (e == 1) ? bv1 : (e == 2) ? bv2 : bv3;
            const int   bi = (e == 0) ? bi0 : (e == 1) ? bi1 : (e == 2) ? bi2 : bi3;
            if (bv > 0.f) {
                const int row = b * NA + bi;
                const int pos = atomicAdd(&counts[row], 1);
                if (pos < CAP) {
                    const unsigned long long key =
                        ((unsigned long long)__float_as_uint(bv) << 32) |
                        (unsigned)(~(t0 + e));
                    lists[(size_t)row * CAP + pos] = key;
                }
            }
        }
    }
}

// k2: one THREAD per row. Top-16 of the ~8 candidates via 16-slot register
// insertion (keys order by value desc, tie -> lower t), zero-fill via a
// per-thread LDS bitmap of candidate t's.
__global__ __launch_bounds__(64) void k2_select(
    const int* __restrict__ counts, const unsigned long long* __restrict__ lists,
    float* __restrict__ feat, float* __restrict__ idx_out) {
    __shared__ unsigned bm[64][65];              // +1 pad: (lane+w)%32 banks
    const int lane = threadIdx.x;
    const int row  = blockIdx.x * 64 + lane;
    unsigned* mybm = bm[lane];
    #pragma unroll
    for (int w = 0; w < NT / 32; ++w) mybm[w] = 0u;

    int n = counts[row];
    if (n > CAP) n = CAP;
    const unsigned long long* L = lists + (size_t)row * CAP;

    unsigned long long best[NK];
    #pragma unroll
    for (int k = 0; k < NK; ++k) best[k] = 0ull;

    for (int i = 0; i < n; ++i) {
        unsigned long long c = L[i];
        const unsigned t = ~(unsigned)c & (NT - 1);
        mybm[t >> 5] |= 1u << (t & 31);
        #pragma unroll
        for (int k = 0; k < NK; ++k) {           // bubble c down (static indices)
            const unsigned long long hi = best[k] > c ? best[k] : c;
            const unsigned long long lo = best[k] > c ? c : best[k];
            best[k] = hi; c = lo;
        }
    }

    const int nsel = (n < NK) ? n : NK;
    float* frow = feat + (size_t)row * NT;
    float* irow = idx_out + (size_t)row * NK;
    #pragma unroll
    for (int k = 0; k < NK; ++k) {
        if (k < nsel) {
            const unsigned t = ~(unsigned)best[k] & (NT - 1);
            irow[k] = (float)t;
            frow[t] = 1.0f;
        }
    }
    // zero-fill: smallest t's not in the candidate set
    int k = nsel;
    for (int w = 0; w < NT / 32 && k < NK; ++w) {
        unsigned z = ~mybm[w];
        while (z && k < NK) {
            const int bit = __ffs(z) - 1;
            z &= z - 1;
            const int t = w * 32 + bit;
            irow[k] = (float)t;
            frow[t] = 1.0f;
            ++k;
        }
    }
}

extern "C" void kernel_launch(void* const* d_in, const int* in_sizes, int n_in,
                              void* d_out, int out_size, void* d_ws, size_t ws_size,
                              hipStream_t stream) {
    const float* x   = (const float*)d_in[0];
    const float* thr = (const float*)d_in[1];

    float* feat    = (float*)d_out;                       // [B,A,T]
    float* idx_out = feat + (size_t)NB * NA * NT;         // [B,A,K] (indices as float)
    float* mask    = idx_out + (size_t)NB * NA * NK;      // [B,A,T]

    int* counts = (int*)d_ws;                                           // [NROWS]
    unsigned long long* lists =
        (unsigned long long*)((char*)d_ws + 65536);                     // [NROWS][CAP]

    (void)hipMemsetAsync(counts, 0, sizeof(int) * NROWS, stream);
    hipLaunchKernelGGL(k1_argmax, dim3(NT / 256, NB), dim3(512), 0, stream,
                       x, thr, feat, mask, counts, lists);
    hipLaunchKernelGGL(k2_select, dim3(NROWS / 64), dim3(64), 0, stream,
                       counts, lists, feat, idx_out);
}